// Round 6
// baseline (1344.910 us; speedup 1.0000x reference)
//
#include <hip/hip_runtime.h>
#include <stdint.h>

// Problem constants
#define BB 64
#define LL 1024
#define DD 1024
#define CC 128
#define STOPTAG 127

// ---------------------------------------------------------------------------
// K1: emis[b*L + l][c] = sum_k x[.][k] * W[k][c] + bias[c]   (pure f32)
// ---------------------------------------------------------------------------
__global__ __launch_bounds__(256) void k_emis(const float* __restrict__ x,
                                              const float* __restrict__ W,
                                              const float* __restrict__ bias,
                                              float* __restrict__ emis) {
    __shared__ float a_t[32][132];
    const int tid = threadIdx.x;
    const int bm  = blockIdx.x;
    const float* A = x + (size_t)bm * 128 * DD;
    const int tx = tid & 15, ty = tid >> 4;
    const int r0 = ty * 8, c0 = tx * 8;

    float acc[8][8];
#pragma unroll
    for (int i = 0; i < 8; ++i)
#pragma unroll
        for (int j = 0; j < 8; ++j) acc[i][j] = 0.0f;

    for (int kc = 0; kc < 32; ++kc) {
        __syncthreads();
#pragma unroll
        for (int i = 0; i < 4; ++i) {
            int s   = tid + 256 * i;
            int row = s >> 3;
            int k0  = (s & 7) * 4;
            float4 v = *(const float4*)(A + (size_t)row * DD + kc * 32 + k0);
            a_t[k0 + 0][row] = v.x;
            a_t[k0 + 1][row] = v.y;
            a_t[k0 + 2][row] = v.z;
            a_t[k0 + 3][row] = v.w;
        }
        __syncthreads();
        const float* Wp = W + (size_t)kc * 32 * CC;
#pragma unroll
        for (int k = 0; k < 32; ++k) {
            float4 w0 = *(const float4*)(Wp + k * CC + c0);
            float4 w1 = *(const float4*)(Wp + k * CC + c0 + 4);
            float4 pa = *(const float4*)&a_t[k][r0];
            float4 pb = *(const float4*)&a_t[k][r0 + 4];
            float av[8] = {pa.x, pa.y, pa.z, pa.w, pb.x, pb.y, pb.z, pb.w};
            float wv[8] = {w0.x, w0.y, w0.z, w0.w, w1.x, w1.y, w1.z, w1.w};
#pragma unroll
            for (int i = 0; i < 8; ++i)
#pragma unroll
                for (int j = 0; j < 8; ++j)
                    acc[i][j] = fmaf(av[i], wv[j], acc[i][j]);
        }
    }
    float4 bv0 = *(const float4*)(bias + c0);
    float4 bv1 = *(const float4*)(bias + c0 + 4);
    float bb[8] = {bv0.x, bv0.y, bv0.z, bv0.w, bv1.x, bv1.y, bv1.z, bv1.w};
#pragma unroll
    for (int i = 0; i < 8; ++i) {
        size_t row = (size_t)bm * 128 + r0 + i;
        float4 o0 = make_float4(acc[i][0] + bb[0], acc[i][1] + bb[1],
                                acc[i][2] + bb[2], acc[i][3] + bb[3]);
        float4 o1 = make_float4(acc[i][4] + bb[4], acc[i][5] + bb[5],
                                acc[i][6] + bb[6], acc[i][7] + bb[7]);
        *(float4*)(emis + row * CC + c0)     = o0;
        *(float4*)(emis + row * CC + c0 + 4) = o1;
    }
}

// ---------------------------------------------------------------------------
// K2: Viterbi forward. 8 waves/batch. Step loop is PURE LDS+VALU:
//  - emis staged via double-buffered ldsE chunks of 16 rows (reg-staged
//    issue-early/publish-late), scores buffered in ldsS and flushed as
//    coalesced float4 stores once per 16 steps -> no per-step vmem waits.
//  - partials in part[2][CC][12] (48B stride): combine = 2x ds_read_b128
//    + 4-instr max tree (was 8x b32). Writes 8-way conflicted (cheap).
//  - raw s_barrier + lgkmcnt-only waits; vmem stays in flight across steps.
// Mask may arrive as 1-byte bool or int32; discriminator byte [1] (len>=512).
// ---------------------------------------------------------------------------
__global__ __launch_bounds__(512) void k_forward(float* __restrict__ emis,
                                                 const unsigned char* __restrict__ mask,
                                                 const float* __restrict__ T) {
    const int b    = blockIdx.x;
    const int tid  = threadIdx.x;
    const int w    = tid >> 6;
    const int lane = tid & 63;
    const int trow = tid >> 5;          // 0..15 (chunk row)
    const int tcol = (tid & 31) * 4;    // 0..124 (chunk col, float4)

    __shared__ __align__(16) float part[2][CC][12];
    __shared__ __align__(16) float ldsE[2][16][CC];
    __shared__ __align__(16) float ldsS[2][16][CC];
    __shared__ int s_len;
    if (tid == 0) s_len = 0;
    __syncthreads();

    // sequence length (prefix mask -> popcount); 256 threads cover 1024 elems
    if (tid < 256) {
        const bool is_b8 = (mask[1] != 0);
        int c;
        if (is_b8) {
            const uchar4* m4 = (const uchar4*)(mask + (size_t)b * LL);
            uchar4 mv = m4[tid];
            c = (mv.x != 0) + (mv.y != 0) + (mv.z != 0) + (mv.w != 0);
        } else {
            const int4* m4 = (const int4*)((const int*)(const void*)mask + (size_t)b * LL);
            int4 mv = m4[tid];
            c = (mv.x != 0) + (mv.y != 0) + (mv.z != 0) + (mv.w != 0);
        }
        atomicAdd(&s_len, c);
    }
    __syncthreads();
    const int len = s_len;                    // >= 512

    // T columns for this lane over the wave's 16-wide cp window
    float t0[16], t1[16];
#pragma unroll
    for (int j = 0; j < 16; ++j) {
        t0[j] = T[(size_t)(w * 16 + j) * CC + lane];
        t1[j] = T[(size_t)(w * 16 + j) * CC + lane + 64];
    }

    const int cc_fin = w * 16 + (lane & 15);
    float* eb = emis + (size_t)b * LL * CC;   // emis rows become score rows in place

    // prologue: chunks 0,1 -> ldsE; chunk 2 staged in regs
    float4 rs;
    {
        float4 c0v = *(const float4*)(eb + (size_t)trow * CC + tcol);
        float4 c1v = *(const float4*)(eb + (size_t)(16 + trow) * CC + tcol);
        *(float4*)&ldsE[0][trow][tcol] = c0v;
        *(float4*)&ldsE[1][trow][tcol] = c1v;
        rs = *(const float4*)(eb + (size_t)(32 + trow) * CC + tcol);
    }
    __syncthreads();

    float s_val = 0.0f;

    for (int l = 0; l < len; ++l) {
        if ((l & 15) == 0 && l > 0) {         // chunk boundary, uniform branch
            const int c = l >> 4;
            asm volatile("s_waitcnt lgkmcnt(0)" ::: "memory");
            __builtin_amdgcn_s_barrier();
            asm volatile("" ::: "memory");
            // flush score chunk c-1 (rows 16(c-1)..16c-1, all < len)
            float4 v = *(const float4*)&ldsS[(c - 1) & 1][trow][tcol];
            *(float4*)(eb + (size_t)(16 * (c - 1) + trow) * CC + tcol) = v;
            // publish staged emis chunk c+1
            *(float4*)&ldsE[(c + 1) & 1][trow][tcol] = rs;
            // stage emis chunk c+2 (clamped; row len-1 is never overwritten in-loop)
            int g = 16 * (c + 2) + trow;
            g = g < len ? g : len - 1;
            rs = *(const float4*)(eb + (size_t)g * CC + tcol);
        }

        // MAC over own cp window (wave-local readlane broadcast)
        float acc0 = -INFINITY, acc1 = -INFINITY;
#pragma unroll
        for (int jj = 0; jj < 8; ++jj) {
            float sa = __int_as_float(__builtin_amdgcn_readlane(__float_as_int(s_val), 2 * jj));
            float sb = __int_as_float(__builtin_amdgcn_readlane(__float_as_int(s_val), 2 * jj + 1));
            acc0 = fmaxf(fmaxf(sa + t0[2 * jj], sb + t0[2 * jj + 1]), acc0);
            acc1 = fmaxf(fmaxf(sa + t1[2 * jj], sb + t1[2 * jj + 1]), acc1);
        }
        const int p = l & 1;
        part[p][lane][w]      = acc0;
        part[p][lane + 64][w] = acc1;
        asm volatile("s_waitcnt lgkmcnt(0)" ::: "memory");
        __builtin_amdgcn_s_barrier();
        asm volatile("" ::: "memory");

        // combine: 2x b128 + max tree + e from ldsE
        float4 q0 = *(const float4*)&part[p][cc_fin][0];
        float4 q1 = *(const float4*)&part[p][cc_fin][4];
        float m01 = fmaxf(q0.x, q0.y), m23 = fmaxf(q0.z, q0.w);
        float m45 = fmaxf(q1.x, q1.y), m67 = fmaxf(q1.z, q1.w);
        float mx  = fmaxf(fmaxf(m01, m23), fmaxf(m45, m67));
        s_val = mx + ldsE[(l >> 4) & 1][l & 15][cc_fin];
        if (lane < 16) ldsS[(l >> 4) & 1][l & 15][cc_fin] = s_val;
    }

    // epilogue: flush final (possibly partial) chunk
    asm volatile("s_waitcnt lgkmcnt(0)" ::: "memory");
    __syncthreads();
    {
        const int cf = (len - 1) >> 4;
        float4 v = *(const float4*)&ldsS[cf & 1][trow][tcol];
        int g = 16 * cf + trow;
        if (g < len) *(float4*)(eb + (size_t)g * CC + tcol) = v;
    }
}

// ---------------------------------------------------------------------------
// K3: backtrack. One wave per batch. Exact first-index argmax per step
// (monotonic-u32 keys, DPP max reduction, ballot+ctz).
// ---------------------------------------------------------------------------
__device__ __forceinline__ unsigned mono_u32(float f) {
    unsigned u = __float_as_uint(f);
    return u ^ (unsigned)(((int)u >> 31) | 0x80000000);
}

__device__ __forceinline__ unsigned dpp_max64(unsigned m) {
    unsigned t;
    t = (unsigned)__builtin_amdgcn_update_dpp(0, (int)m, 0x111, 0xF, 0xF, true); m = m > t ? m : t;
    t = (unsigned)__builtin_amdgcn_update_dpp(0, (int)m, 0x112, 0xF, 0xF, true); m = m > t ? m : t;
    t = (unsigned)__builtin_amdgcn_update_dpp(0, (int)m, 0x114, 0xF, 0xF, true); m = m > t ? m : t;
    t = (unsigned)__builtin_amdgcn_update_dpp(0, (int)m, 0x118, 0xF, 0xF, true); m = m > t ? m : t;
    t = (unsigned)__builtin_amdgcn_update_dpp(0, (int)m, 0x142, 0xF, 0xF, true); m = m > t ? m : t;
    t = (unsigned)__builtin_amdgcn_update_dpp(0, (int)m, 0x143, 0xF, 0xF, true); m = m > t ? m : t;
    return m;   // lane 63 holds the wave max
}

__device__ __forceinline__ int astep(float sA, float sB, int row,
                                     const float* ldsT, int lane) {
    int q = (row & 7) << 2;
    float c0 = sA + ldsT[row * CC + (lane ^ q)];
    float c1 = sB + ldsT[row * CC + ((lane ^ q) + 64)];
    unsigned m0 = mono_u32(c0), m1 = mono_u32(c1);
    unsigned m = m0 > m1 ? m0 : m1;
    m = dpp_max64(m);
    unsigned mx = (unsigned)__builtin_amdgcn_readlane((int)m, 63);
    unsigned long long bl0 = __ballot(m0 == mx);
    unsigned long long bl1 = __ballot(m1 == mx);
    return bl0 ? __builtin_ctzll(bl0) : (64 + __builtin_ctzll(bl1));
}

__global__ __launch_bounds__(64) void k_back(const float* __restrict__ slog,
                                             const unsigned char* __restrict__ mask,
                                             const float* __restrict__ T,
                                             int* __restrict__ out) {
    const int b    = blockIdx.x;
    const int lane = threadIdx.x;
    __shared__ float ldsT[CC * CC];

    {
        int q = (lane & 7) << 2;
        for (int r = 0; r < CC; ++r) {
            float v0 = T[(size_t)r * CC + lane];
            float v1 = T[(size_t)r * CC + lane + 64];
            ldsT[lane * CC + (r ^ q)]        = v0;
            ldsT[(lane + 64) * CC + (r ^ q)] = v1;
        }
    }
    int len = 0;
    {
        const bool is_b8 = (mask[1] != 0);
        if (is_b8) {
            const unsigned char* mrow = mask + (size_t)b * LL;
            for (int i = 0; i < 16; ++i)
                len += (int)__popcll(__ballot(mrow[lane + i * 64] != 0));
        } else {
            const int* mrow = (const int*)(const void*)mask + (size_t)b * LL;
            for (int i = 0; i < 16; ++i)
                len += (int)__popcll(__ballot(mrow[lane + i * 64] != 0));
        }
    }
    __syncthreads();

    const float* sb = slog + (size_t)b * LL * CC;
    int* ob         = out + (size_t)b * LL;

    for (int l = len + lane; l < LL; l += 64) ob[l] = 0;

    float f0 = sb[(size_t)(len - 1) * CC + lane];
    float f1 = sb[(size_t)(len - 1) * CC + lane + 64];
    int cur = astep(f0, f1, STOPTAG, ldsT, lane);
    if (lane == 0) ob[len - 1] = cur;

    int r = len - 2;
    float a0 = sb[(size_t)r * CC + lane];
    float a1 = sb[(size_t)r * CC + lane + 64];
    float b0 = sb[(size_t)(r - 1) * CC + lane];
    float b1 = sb[(size_t)(r - 1) * CC + lane + 64];
    while (r >= 2) {
        int rc = r - 2;
        int rd = r - 3 >= 0 ? r - 3 : 0;
        float n0 = sb[(size_t)rc * CC + lane];
        float n1 = sb[(size_t)rc * CC + lane + 64];
        float p0 = sb[(size_t)rd * CC + lane];
        float p1 = sb[(size_t)rd * CC + lane + 64];
        cur = astep(a0, a1, cur, ldsT, lane);
        if (lane == 0) ob[r] = cur;
        cur = astep(b0, b1, cur, ldsT, lane);
        if (lane == 0) ob[r - 1] = cur;
        a0 = n0; a1 = n1; b0 = p0; b1 = p1;
        r -= 2;
    }
    if (r == 1) {
        cur = astep(a0, a1, cur, ldsT, lane);
        if (lane == 0) ob[1] = cur;
        cur = astep(b0, b1, cur, ldsT, lane);
        if (lane == 0) ob[0] = cur;
    } else if (r == 0) {
        cur = astep(a0, a1, cur, ldsT, lane);
        if (lane == 0) ob[0] = cur;
    }
}

// ---------------------------------------------------------------------------
extern "C" void kernel_launch(void* const* d_in, const int* in_sizes, int n_in,
                              void* d_out, int out_size, void* d_ws, size_t ws_size,
                              hipStream_t stream) {
    (void)in_sizes; (void)n_in; (void)out_size; (void)ws_size;
    const float* x    = (const float*)d_in[0];
    const unsigned char* mask = (const unsigned char*)d_in[1];
    // d_in[2] = y (unused by the reference output)
    const float* W    = (const float*)d_in[3];
    const float* bias = (const float*)d_in[4];
    const float* T    = (const float*)d_in[5];
    int* out = (int*)d_out;

    float* emis = (float*)d_ws;   // 32 MB; score rows overwrite emis in place

    k_emis<<<dim3(512), dim3(256), 0, stream>>>(x, W, bias, emis);
    k_forward<<<dim3(BB), dim3(512), 0, stream>>>(emis, mask, T);
    k_back<<<dim3(BB), dim3(64), 0, stream>>>(emis, mask, T, out);
}